// Round 7
// baseline (5275.628 us; speedup 1.0000x reference)
//
#include <hip/hip_runtime.h>
#include <hip/hip_bf16.h>
#include <math.h>

#define BT 8192      // B*T rows
#define C_ 1024
#define N3 3072
#define T_ 2048

typedef double v4d __attribute__((ext_vector_type(4)));

// f64 MFMA 16x16x4 layouts (HW-verified via round-3 exact-integer probe):
//   A: m = l&15, k = l>>4        B: k = l>>4, n = l&15
//   D: col = l&15, row = (l>>4) + 4*reg      <-- NOT 4*(l>>4)+reg

// =====================================================================
// Kernel A: qkv = x @ w_qkv via f64 MFMA, 128x128 tile, BK=32.
// (measured ~94% of f64 MFMA peak — unchanged)
// =====================================================================
__device__ __forceinline__ void qkv_loadA(const float* __restrict__ X, int bm, int k0,
                                          int t, float4* fa) {
#pragma unroll
  for (int i = 0; i < 4; i++) {
    int idx = i * 256 + t;            // 0..1023 : 128 rows x 8 quads
    int row = idx >> 3, q4 = idx & 7;
    int c4 = q4 ^ (row & 7);          // pre-swizzled source column quad
    fa[i] = *(const float4*)(X + (size_t)(bm + row) * C_ + k0 + 4 * c4);
  }
}
__device__ __forceinline__ void qkv_loadB(const float* __restrict__ W, int bn, int k0,
                                          int t, float4* fb) {
#pragma unroll
  for (int i = 0; i < 4; i++) {
    int idx = i * 256 + t;            // 0..1023 : 32 rows x 32 quads
    int row = idx >> 5, q4 = idx & 31;
    fb[i] = *(const float4*)(W + (size_t)(k0 + row) * N3 + bn + 4 * q4);
  }
}
__device__ __forceinline__ void qkv_storeA(float* Al, int t, const float4* fa) {
  float4* A4 = (float4*)Al;
#pragma unroll
  for (int i = 0; i < 4; i++) {
    int idx = i * 256 + t;
    int row = idx >> 3, q4 = idx & 7;
    A4[row * 8 + q4] = fa[i];         // linear dest; source was pre-swizzled
  }
}
__device__ __forceinline__ void qkv_storeB(float* Bl, int t, const float4* fb) {
  float4* B4 = (float4*)Bl;
#pragma unroll
  for (int i = 0; i < 4; i++) {
    int idx = i * 256 + t;
    int row = idx >> 5, q4 = idx & 31;
    B4[row * 32 + q4] = fb[i];
  }
}

__global__ __launch_bounds__(256, 2) void qkv_mfma(const float* __restrict__ X,
                                                   const float* __restrict__ W,
                                                   double* __restrict__ QKV) {
  const int bn = blockIdx.x * 128, bm = blockIdx.y * 128;
  const int t = threadIdx.x;
  const int w = t >> 6, l = t & 63, g = l >> 4, ln = l & 15;
  const int m0 = (w >> 1) * 64, n0 = (w & 1) * 64;   // wave's 64x64 sub-tile

  __shared__ float Al[2][128 * 32];
  __shared__ float Bl[2][32 * 128];

  v4d acc[4][4];
#pragma unroll
  for (int i = 0; i < 4; i++)
#pragma unroll
    for (int j = 0; j < 4; j++) acc[i][j] = (v4d){0.0, 0.0, 0.0, 0.0};

  float4 fa[4], fb[4];
  qkv_loadA(X, bm, 0, t, fa);
  qkv_loadB(W, bn, 0, t, fb);
  qkv_storeA(Al[0], t, fa);
  qkv_storeB(Bl[0], t, fb);
  __syncthreads();

  for (int st = 0; st < 32; ++st) {
    const int cur = st & 1;
    if (st + 1 < 32) {                 // prefetch next stage into regs
      qkv_loadA(X, bm, (st + 1) * 32, t, fa);
      qkv_loadB(W, bn, (st + 1) * 32, t, fb);
    }
    const float* Ac = Al[cur];
    const float* Bc = Bl[cur];
#pragma unroll
    for (int s = 0; s < 8; s++) {      // 8 K-steps of 4
      double a[4], b[4];
#pragma unroll
      for (int mt = 0; mt < 4; mt++) {
        int row = m0 + mt * 16 + ln;
        a[mt] = (double)Ac[row * 32 + ((s ^ (row & 7)) << 2) + g];
      }
#pragma unroll
      for (int nt = 0; nt < 4; nt++)
        b[nt] = (double)Bc[(4 * s + g) * 128 + n0 + nt * 16 + ln];
#pragma unroll
      for (int mt = 0; mt < 4; mt++)
#pragma unroll
        for (int nt = 0; nt < 4; nt++)
          acc[mt][nt] = __builtin_amdgcn_mfma_f64_16x16x4f64(a[mt], b[nt], acc[mt][nt], 0, 0, 0);
    }
    if (st + 1 < 32) {
      qkv_storeA(Al[cur ^ 1], t, fa);
      qkv_storeB(Bl[cur ^ 1], t, fb);
    }
    __syncthreads();
  }

  // D row = g + 4r (verified layout)
#pragma unroll
  for (int mt = 0; mt < 4; mt++)
#pragma unroll
    for (int nt = 0; nt < 4; nt++)
#pragma unroll
      for (int r = 0; r < 4; r++) {
        size_t row = (size_t)(bm + m0 + mt * 16 + g + 4 * r);
        QKV[row * N3 + bn + n0 + nt * 16 + ln] = acc[mt][nt][r];
      }
}

// =====================================================================
// Kernel B: causal (QK^T/8) V via f64 MFMA — PAIRED q-tiles.
// Block processes q-tile pairs (2i, 2i+1) together: one K/V LDS tile
// feeds both q-sets (2x MFMA per LDS/HBM byte, half the barriers).
// Passes {i=15-px, i=px} -> constant 68 K-tiles/block; grid 8x64 = 2/CU.
// K-tile = 32, double-buffered XOR-swizzled 64 KB LDS. S^T = K*Q^T.
// =====================================================================
struct KVregs { double2 k[4]; double2 v[4]; };

__device__ __forceinline__ void kv_load(const double* __restrict__ QKV, size_t tokbase,
                                        int h, int kt, int t, KVregs& R) {
#pragma unroll
  for (int i = 0; i < 4; i++) {
    int idx = i * 256 + t;             // 0..1023 : 32 rows x 32 double2 slots
    int r = idx >> 5, q2 = idx & 31;
    int c2 = q2 ^ (r & 15);            // inverse-swizzled source pair
    size_t off = (tokbase + (size_t)(kt * 32 + r)) * N3 + h * 64 + 2 * c2;
    R.k[i] = *(const double2*)(QKV + off + C_);
    R.v[i] = *(const double2*)(QKV + off + 2 * C_);
  }
}
__device__ __forceinline__ void kv_store(double2* Kb, double2* Vb, int t, const KVregs& R) {
#pragma unroll
  for (int i = 0; i < 4; i++) {
    int idx = i * 256 + t;
    int r = idx >> 5, q2 = idx & 31;
    Kb[r * 32 + q2] = R.k[i];
    Vb[r * 32 + q2] = R.v[i];
  }
}

__global__ __launch_bounds__(256, 2) void attn_mfma(const double* __restrict__ QKV,
                                                    double* __restrict__ LOGITS) {
  const int px = blockIdx.x;                // 0..7
  const int bh = blockIdx.y;
  const int b = bh >> 4, h = bh & 15;
  const int t = threadIdx.x;
  const int w = t >> 6, l = t & 63, g = l >> 4, ln = l & 15;
  const size_t tokbase = (size_t)b * T_;

  __shared__ double2 Kl[2][1024];
  __shared__ double2 Vl[2][1024];

  for (int pass = 0; pass < 2; ++pass) {
    const int i = pass ? px : 15 - px;      // pair index; nkt = 4i+4; sum = 68
    const int qtA = 2 * i, qtB = 2 * i + 1;
    const int qrowA = qtA * 64 + w * 16 + ln;
    const int qrowB = qtB * 64 + w * 16 + ln;
    const int qmaxA = qtA * 64 + w * 16 + 15;
    const int qmaxB = qtB * 64 + w * 16 + 15;

    // Q fragments for both q-sets: Q[qrow][4s+g]
    double qfA[16], qfB[16];
#pragma unroll
    for (int s = 0; s < 16; s++) {
      qfA[s] = QKV[(tokbase + (size_t)qrowA) * N3 + h * 64 + 4 * s + g];
      qfB[s] = QKV[(tokbase + (size_t)qrowB) * N3 + h * 64 + 4 * s + g];
    }

    v4d accA[4], accB[4];
#pragma unroll
    for (int nt = 0; nt < 4; nt++) {
      accA[nt] = (v4d){0.0, 0.0, 0.0, 0.0};
      accB[nt] = (v4d){0.0, 0.0, 0.0, 0.0};
    }

    const int nkt = 4 * i + 4;
    KVregs R;
    kv_load(QKV, tokbase, h, 0, t, R);
    kv_store(Kl[0], Vl[0], t, R);
    __syncthreads();

    for (int kt = 0; kt < nkt; ++kt) {
      const int cur = kt & 1;
      if (kt + 1 < nkt) kv_load(QKV, tokbase, h, kt + 1, t, R);
      const double* Kd = (const double*)Kl[cur];
      const double* Vd = (const double*)Vl[cur];

      // ---- QK: S^T tiles for both q-sets, shared K reads ----
      // smX[mt][r] = S[k_local = mt*16 + g + 4r][q = ln]
      double smA[2][4], smB[2][4];
#pragma unroll
      for (int mt = 0; mt < 2; mt++) {
        v4d sA = (v4d){0.0, 0.0, 0.0, 0.0};
        v4d sB = (v4d){0.0, 0.0, 0.0, 0.0};
        const bool actA = (kt * 32 + mt * 16 <= qmaxA);   // wave-uniform
        const bool actB = (kt * 32 + mt * 16 <= qmaxB);   // superset of actA
        if (actB) {
          const int r = mt * 16 + ln;       // K row (local)
#pragma unroll
          for (int s = 0; s < 16; s++) {
            int c = 4 * s + g;
            double a = Kd[r * 64 + (((c >> 1) ^ (r & 15)) << 1) + (c & 1)];
            sB = __builtin_amdgcn_mfma_f64_16x16x4f64(a, qfB[s], sB, 0, 0, 0);
            if (actA)
              sA = __builtin_amdgcn_mfma_f64_16x16x4f64(a, qfA[s], sA, 0, 0, 0);
          }
        }
#pragma unroll
        for (int r = 0; r < 4; r++) {
          int kg = kt * 32 + mt * 16 + g + 4 * r;   // verified D row = g + 4r
          smA[mt][r] = (kg <= qrowA) ? sA[r] * 0.125 : 0.0;
          smB[mt][r] = (kg <= qrowB) ? sB[r] * 0.125 : 0.0;
        }
      }

      // ---- PV: O += S * V for both q-sets, shared V reads ----
#pragma unroll
      for (int s = 0; s < 8; s++) {
        const bool actA = (kt * 32 + 4 * s <= qmaxA);     // wave-uniform
        const bool actB = (kt * 32 + 4 * s <= qmaxB);
        if (actB) {
          double aA = smA[s >> 2][s & 3];   // = S_A[q=ln][4s+g]
          double aB = smB[s >> 2][s & 3];
          const int rv = 4 * s + g;         // V row (local)
#pragma unroll
          for (int nt = 0; nt < 4; nt++) {
            int cv = nt * 16 + ln;
            double bb = Vd[rv * 64 + (((cv >> 1) ^ (rv & 15)) << 1) + (cv & 1)];
            accB[nt] = __builtin_amdgcn_mfma_f64_16x16x4f64(aB, bb, accB[nt], 0, 0, 0);
            if (actA)
              accA[nt] = __builtin_amdgcn_mfma_f64_16x16x4f64(aA, bb, accA[nt], 0, 0, 0);
          }
        }
      }

      if (kt + 1 < nkt) kv_store(Kl[cur ^ 1], Vl[cur ^ 1], t, R);
      __syncthreads();
    }

    // O row = g + 4r (verified layout), both q-sets
#pragma unroll
    for (int nt = 0; nt < 4; nt++)
#pragma unroll
      for (int r = 0; r < 4; r++) {
        size_t rowA = tokbase + (size_t)(qtA * 64 + w * 16 + g + 4 * r);
        size_t rowB = tokbase + (size_t)(qtB * 64 + w * 16 + g + 4 * r);
        LOGITS[rowA * C_ + h * 64 + nt * 16 + ln] = accA[nt][r];
        LOGITS[rowB * C_ + h * 64 + nt * 16 + ln] = accB[nt][r];
      }
    // trailing __syncthreads of last kt ordered all LDS reads before next pass
  }
}

// =====================================================================
// Kernel C: LN + softmax + log-transform + mask  (f64 reductions)
// =====================================================================
__device__ __forceinline__ double blockReduceSumD(double val, double* sh) {
#pragma unroll
  for (int off = 32; off > 0; off >>= 1) val += __shfl_down(val, off, 64);
  int wid = threadIdx.x >> 6, lane = threadIdx.x & 63;
  if (lane == 0) sh[wid] = val;
  __syncthreads();
  double total = sh[0] + sh[1] + sh[2] + sh[3];
  __syncthreads();
  return total;
}
__device__ __forceinline__ double blockReduceMaxD(double val, double* sh) {
#pragma unroll
  for (int off = 32; off > 0; off >>= 1) val = fmax(val, __shfl_down(val, off, 64));
  int wid = threadIdx.x >> 6, lane = threadIdx.x & 63;
  if (lane == 0) sh[wid] = val;
  __syncthreads();
  double total = fmax(fmax(sh[0], sh[1]), fmax(sh[2], sh[3]));
  __syncthreads();
  return total;
}

__global__ __launch_bounds__(256) void finish_kernel(const double* __restrict__ LOGITS,
                                                     const float* __restrict__ LNW,
                                                     const float* __restrict__ X,
                                                     const float* __restrict__ NOISE,
                                                     float* __restrict__ OUT,
                                                     double log_scale, double denom) {
  __shared__ double sh[4];
  const int row = blockIdx.x;
  const int t = threadIdx.x;
  const double* lrow = LOGITS + (size_t)row * C_;
  double v[4];
#pragma unroll
  for (int j = 0; j < 4; j++) v[j] = lrow[t + j * 256];
  double psum = v[0] + v[1] + v[2] + v[3];
  double mu = blockReduceSumD(psum, sh) * (1.0 / 1024.0);
  double d2 = 0.0;
#pragma unroll
  for (int j = 0; j < 4; j++) { double d = v[j] - mu; d2 += d * d; }
  double var = blockReduceSumD(d2, sh) * (1.0 / 1024.0);
  double rstd = 1.0 / sqrt(var + 1e-5);
  double z[4];
#pragma unroll
  for (int j = 0; j < 4; j++)
    z[j] = (v[j] - mu) * rstd * (double)LNW[t + j * 256];
  double zmax = fmax(fmax(z[0], z[1]), fmax(z[2], z[3]));
  double m = blockReduceMaxD(zmax, sh);
  double e[4];
  double esum = 0.0;
#pragma unroll
  for (int j = 0; j < 4; j++) { e[j] = exp(z[j] - m); esum += e[j]; }
  double stot = blockReduceSumD(esum, sh);
#pragma unroll
  for (int j = 0; j < 4; j++) {
    int col = t + j * 256;
    double p = e[j] / stot;
    double sc = log(log_scale * p + 1.0) / denom;
    double comp = 1.0 - sc;
    double nz = (double)NOISE[(size_t)row * C_ + col];
    double maskv = (nz >= comp) ? (comp + sc) : ((comp - 1.0) + sc);
    OUT[(size_t)row * C_ + col] = (float)((double)X[(size_t)row * C_ + col] * maskv);
  }
}

// =====================================================================
extern "C" void kernel_launch(void* const* d_in, const int* in_sizes, int n_in,
                              void* d_out, int out_size, void* d_ws, size_t ws_size,
                              hipStream_t stream) {
  const float* X = (const float*)d_in[0];
  const float* W = (const float*)d_in[1];
  const float* LNW = (const float*)d_in[2];
  const float* NOISE = (const float*)d_in[3];
  float* OUT = (float*)d_out;

  double* qkv = (double*)d_ws;                                  // 192 MB
  double* logits = (double*)((char*)d_ws + 8ull * BT * N3);     // +64 MB

  const double e = 1.0 / 1024.0;
  const double ls = (1.0 + sqrt(1.0 - 4.0 * e) - 2.0 * e) / (2.0 * e * e);
  const double denom = log(ls);

  qkv_mfma<<<dim3(N3 / 128, BT / 128), 256, 0, stream>>>(X, W, qkv);
  attn_mfma<<<dim3(8, 64), 256, 0, stream>>>(qkv, logits);
  finish_kernel<<<BT, 256, 0, stream>>>(logits, LNW, X, NOISE, OUT, ls, denom);
}

// Round 8
// 2411.388 us; speedup vs baseline: 2.1878x; 2.1878x over previous
//
#include <hip/hip_runtime.h>
#include <hip/hip_bf16.h>
#include <math.h>

#define BT 8192      // B*T rows
#define C_ 1024
#define N3 3072
#define T_ 2048

typedef double v4d __attribute__((ext_vector_type(4)));

// f64 MFMA 16x16x4 layouts (HW-verified via round-3 exact-integer probe):
//   A: m = l&15, k = l>>4        B: k = l>>4, n = l&15
//   D: col = l&15, row = (l>>4) + 4*reg      <-- NOT 4*(l>>4)+reg

// =====================================================================
// Kernel A: qkv = x @ w_qkv via f64 MFMA, 128x128 tile, BK=32.
// (measured ~94% of f64 MFMA peak — unchanged)
// =====================================================================
__device__ __forceinline__ void qkv_loadA(const float* __restrict__ X, int bm, int k0,
                                          int t, float4* fa) {
#pragma unroll
  for (int i = 0; i < 4; i++) {
    int idx = i * 256 + t;            // 0..1023 : 128 rows x 8 quads
    int row = idx >> 3, q4 = idx & 7;
    int c4 = q4 ^ (row & 7);          // pre-swizzled source column quad
    fa[i] = *(const float4*)(X + (size_t)(bm + row) * C_ + k0 + 4 * c4);
  }
}
__device__ __forceinline__ void qkv_loadB(const float* __restrict__ W, int bn, int k0,
                                          int t, float4* fb) {
#pragma unroll
  for (int i = 0; i < 4; i++) {
    int idx = i * 256 + t;            // 0..1023 : 32 rows x 32 quads
    int row = idx >> 5, q4 = idx & 31;
    fb[i] = *(const float4*)(W + (size_t)(k0 + row) * N3 + bn + 4 * q4);
  }
}
__device__ __forceinline__ void qkv_storeA(float* Al, int t, const float4* fa) {
  float4* A4 = (float4*)Al;
#pragma unroll
  for (int i = 0; i < 4; i++) {
    int idx = i * 256 + t;
    int row = idx >> 3, q4 = idx & 7;
    A4[row * 8 + q4] = fa[i];         // linear dest; source was pre-swizzled
  }
}
__device__ __forceinline__ void qkv_storeB(float* Bl, int t, const float4* fb) {
  float4* B4 = (float4*)Bl;
#pragma unroll
  for (int i = 0; i < 4; i++) {
    int idx = i * 256 + t;
    int row = idx >> 5, q4 = idx & 31;
    B4[row * 32 + q4] = fb[i];
  }
}

__global__ __launch_bounds__(256, 2) void qkv_mfma(const float* __restrict__ X,
                                                   const float* __restrict__ W,
                                                   double* __restrict__ QKV) {
  const int bn = blockIdx.x * 128, bm = blockIdx.y * 128;
  const int t = threadIdx.x;
  const int w = t >> 6, l = t & 63, g = l >> 4, ln = l & 15;
  const int m0 = (w >> 1) * 64, n0 = (w & 1) * 64;   // wave's 64x64 sub-tile

  __shared__ float Al[2][128 * 32];
  __shared__ float Bl[2][32 * 128];

  v4d acc[4][4];
#pragma unroll
  for (int i = 0; i < 4; i++)
#pragma unroll
    for (int j = 0; j < 4; j++) acc[i][j] = (v4d){0.0, 0.0, 0.0, 0.0};

  float4 fa[4], fb[4];
  qkv_loadA(X, bm, 0, t, fa);
  qkv_loadB(W, bn, 0, t, fb);
  qkv_storeA(Al[0], t, fa);
  qkv_storeB(Bl[0], t, fb);
  __syncthreads();

  for (int st = 0; st < 32; ++st) {
    const int cur = st & 1;
    if (st + 1 < 32) {                 // prefetch next stage into regs
      qkv_loadA(X, bm, (st + 1) * 32, t, fa);
      qkv_loadB(W, bn, (st + 1) * 32, t, fb);
    }
    const float* Ac = Al[cur];
    const float* Bc = Bl[cur];
#pragma unroll
    for (int s = 0; s < 8; s++) {      // 8 K-steps of 4
      double a[4], b[4];
#pragma unroll
      for (int mt = 0; mt < 4; mt++) {
        int row = m0 + mt * 16 + ln;
        a[mt] = (double)Ac[row * 32 + ((s ^ (row & 7)) << 2) + g];
      }
#pragma unroll
      for (int nt = 0; nt < 4; nt++)
        b[nt] = (double)Bc[(4 * s + g) * 128 + n0 + nt * 16 + ln];
#pragma unroll
      for (int mt = 0; mt < 4; mt++)
#pragma unroll
        for (int nt = 0; nt < 4; nt++)
          acc[mt][nt] = __builtin_amdgcn_mfma_f64_16x16x4f64(a[mt], b[nt], acc[mt][nt], 0, 0, 0);
    }
    if (st + 1 < 32) {
      qkv_storeA(Al[cur ^ 1], t, fa);
      qkv_storeB(Bl[cur ^ 1], t, fb);
    }
    __syncthreads();
  }

  // D row = g + 4r (verified layout)
#pragma unroll
  for (int mt = 0; mt < 4; mt++)
#pragma unroll
    for (int nt = 0; nt < 4; nt++)
#pragma unroll
      for (int r = 0; r < 4; r++) {
        size_t row = (size_t)(bm + m0 + mt * 16 + g + 4 * r);
        QKV[row * N3 + bn + n0 + nt * 16 + ln] = acc[mt][nt][r];
      }
}

// =====================================================================
// Kernel B: causal (QK^T/8) V via f64 MFMA — 8-wave 128-row super-tiles.
// Per-wave structure identical to the proven round-6 kernel (112 VGPR,
// no spill); the block is 512 threads so each staged K/V tile feeds
// 128 q-rows (2x reuse, half the barriers/HBM per unit work).
// Super-tile j has nkt=4j+4 K-tiles; passes {15-px, px} -> constant 68.
// Grid 8x64 = 512 blocks = 2/CU (128 KB LDS). S^T = K*Q^T.
// =====================================================================
struct KVregs { double2 k[2]; double2 v[2]; };

__device__ __forceinline__ void kv_load(const double* __restrict__ QKV, size_t tokbase,
                                        int h, int kt, int t, KVregs& R) {
#pragma unroll
  for (int i = 0; i < 2; i++) {
    int idx = i * 512 + t;             // 0..1023 : 32 rows x 32 double2 slots
    int r = idx >> 5, q2 = idx & 31;
    int c2 = q2 ^ (r & 15);            // inverse-swizzled source pair
    size_t off = (tokbase + (size_t)(kt * 32 + r)) * N3 + h * 64 + 2 * c2;
    R.k[i] = *(const double2*)(QKV + off + C_);
    R.v[i] = *(const double2*)(QKV + off + 2 * C_);
  }
}
__device__ __forceinline__ void kv_store(double2* Kb, double2* Vb, int t, const KVregs& R) {
#pragma unroll
  for (int i = 0; i < 2; i++) {
    int idx = i * 512 + t;
    int r = idx >> 5, q2 = idx & 31;
    Kb[r * 32 + q2] = R.k[i];
    Vb[r * 32 + q2] = R.v[i];
  }
}

__global__ __launch_bounds__(512, 4) void attn_mfma(const double* __restrict__ QKV,
                                                    double* __restrict__ LOGITS) {
  const int px = blockIdx.x;                // 0..7
  const int bh = blockIdx.y;
  const int b = bh >> 4, h = bh & 15;
  const int t = threadIdx.x;
  const int w = t >> 6, l = t & 63, g = l >> 4, ln = l & 15;   // w in 0..7
  const size_t tokbase = (size_t)b * T_;

  __shared__ double2 Kl[2][1024];
  __shared__ double2 Vl[2][1024];

  for (int pass = 0; pass < 2; ++pass) {
    const int j = pass ? px : 15 - px;      // super-tile; nkt = 4j+4; sum = 68
    const int qrow = j * 128 + w * 16 + ln; // this lane's q (S^T col)
    const int qmaxw = j * 128 + w * 16 + 15;

    // Q fragments in registers for this pass: Q[qrow][4s+g]
    double qfrag[16];
#pragma unroll
    for (int s = 0; s < 16; s++)
      qfrag[s] = QKV[(tokbase + (size_t)qrow) * N3 + h * 64 + 4 * s + g];

    v4d acco[4];
#pragma unroll
    for (int nt = 0; nt < 4; nt++) acco[nt] = (v4d){0.0, 0.0, 0.0, 0.0};

    const int nkt = 4 * j + 4;
    KVregs R;
    kv_load(QKV, tokbase, h, 0, t, R);
    kv_store(Kl[0], Vl[0], t, R);
    __syncthreads();

    for (int kt = 0; kt < nkt; ++kt) {
      const int cur = kt & 1;
      if (kt + 1 < nkt) kv_load(QKV, tokbase, h, kt + 1, t, R);
      const double* Kd = (const double*)Kl[cur];
      const double* Vd = (const double*)Vl[cur];

      // ---- QK: S^T tiles, 2 independent accum chains per mt ----
      double sm[2][4];
#pragma unroll
      for (int mt = 0; mt < 2; mt++) {
        v4d s4a = (v4d){0.0, 0.0, 0.0, 0.0};
        v4d s4b = (v4d){0.0, 0.0, 0.0, 0.0};
        if (kt * 32 + mt * 16 <= qmaxw) {   // wave-uniform skip of masked tile
          const int r = mt * 16 + ln;       // K row (local)
#pragma unroll
          for (int s = 0; s < 8; s++) {
            int c = 4 * s + g;
            double a = Kd[r * 64 + (((c >> 1) ^ (r & 15)) << 1) + (c & 1)];
            s4a = __builtin_amdgcn_mfma_f64_16x16x4f64(a, qfrag[s], s4a, 0, 0, 0);
          }
#pragma unroll
          for (int s = 8; s < 16; s++) {
            int c = 4 * s + g;
            double a = Kd[r * 64 + (((c >> 1) ^ (r & 15)) << 1) + (c & 1)];
            s4b = __builtin_amdgcn_mfma_f64_16x16x4f64(a, qfrag[s], s4b, 0, 0, 0);
          }
        }
        v4d s4 = s4a + s4b;
#pragma unroll
        for (int r = 0; r < 4; r++) {
          int kg = kt * 32 + mt * 16 + g + 4 * r;   // verified D row = g + 4r
          sm[mt][r] = (kg <= qrow) ? s4[r] * 0.125 : 0.0;
        }
      }

      // ---- PV: O += S * V ; A-frag is lane-local register sm[s>>2][s&3] ----
#pragma unroll
      for (int s = 0; s < 8; s++) {
        if (kt * 32 + 4 * s <= qmaxw) {     // wave-uniform
          double a = sm[s >> 2][s & 3];     // = S[q=ln][4s+g]
          const int rv = 4 * s + g;         // V row (local)
#pragma unroll
          for (int nt = 0; nt < 4; nt++) {
            int cv = nt * 16 + ln;
            double bb = Vd[rv * 64 + (((cv >> 1) ^ (rv & 15)) << 1) + (cv & 1)];
            acco[nt] = __builtin_amdgcn_mfma_f64_16x16x4f64(a, bb, acco[nt], 0, 0, 0);
          }
        }
      }

      if (kt + 1 < nkt) kv_store(Kl[cur ^ 1], Vl[cur ^ 1], t, R);
      __syncthreads();
    }

    // O row = g + 4r (verified layout)
#pragma unroll
    for (int nt = 0; nt < 4; nt++)
#pragma unroll
      for (int r = 0; r < 4; r++) {
        size_t row = tokbase + (size_t)(j * 128 + w * 16 + g + 4 * r);
        LOGITS[row * C_ + h * 64 + nt * 16 + ln] = acco[nt][r];
      }
    // trailing __syncthreads of last kt ordered all LDS reads before next pass
  }
}

// =====================================================================
// Kernel C: LN + softmax + log-transform + mask  (f64 reductions)
// =====================================================================
__device__ __forceinline__ double blockReduceSumD(double val, double* sh) {
#pragma unroll
  for (int off = 32; off > 0; off >>= 1) val += __shfl_down(val, off, 64);
  int wid = threadIdx.x >> 6, lane = threadIdx.x & 63;
  if (lane == 0) sh[wid] = val;
  __syncthreads();
  double total = sh[0] + sh[1] + sh[2] + sh[3];
  __syncthreads();
  return total;
}
__device__ __forceinline__ double blockReduceMaxD(double val, double* sh) {
#pragma unroll
  for (int off = 32; off > 0; off >>= 1) val = fmax(val, __shfl_down(val, off, 64));
  int wid = threadIdx.x >> 6, lane = threadIdx.x & 63;
  if (lane == 0) sh[wid] = val;
  __syncthreads();
  double total = fmax(fmax(sh[0], sh[1]), fmax(sh[2], sh[3]));
  __syncthreads();
  return total;
}

__global__ __launch_bounds__(256) void finish_kernel(const double* __restrict__ LOGITS,
                                                     const float* __restrict__ LNW,
                                                     const float* __restrict__ X,
                                                     const float* __restrict__ NOISE,
                                                     float* __restrict__ OUT,
                                                     double log_scale, double denom) {
  __shared__ double sh[4];
  const int row = blockIdx.x;
  const int t = threadIdx.x;
  const double* lrow = LOGITS + (size_t)row * C_;
  double v[4];
#pragma unroll
  for (int j = 0; j < 4; j++) v[j] = lrow[t + j * 256];
  double psum = v[0] + v[1] + v[2] + v[3];
  double mu = blockReduceSumD(psum, sh) * (1.0 / 1024.0);
  double d2 = 0.0;
#pragma unroll
  for (int j = 0; j < 4; j++) { double d = v[j] - mu; d2 += d * d; }
  double var = blockReduceSumD(d2, sh) * (1.0 / 1024.0);
  double rstd = 1.0 / sqrt(var + 1e-5);
  double z[4];
#pragma unroll
  for (int j = 0; j < 4; j++)
    z[j] = (v[j] - mu) * rstd * (double)LNW[t + j * 256];
  double zmax = fmax(fmax(z[0], z[1]), fmax(z[2], z[3]));
  double m = blockReduceMaxD(zmax, sh);
  double e[4];
  double esum = 0.0;
#pragma unroll
  for (int j = 0; j < 4; j++) { e[j] = exp(z[j] - m); esum += e[j]; }
  double stot = blockReduceSumD(esum, sh);
#pragma unroll
  for (int j = 0; j < 4; j++) {
    int col = t + j * 256;
    double p = e[j] / stot;
    double sc = log(log_scale * p + 1.0) / denom;
    double comp = 1.0 - sc;
    double nz = (double)NOISE[(size_t)row * C_ + col];
    double maskv = (nz >= comp) ? (comp + sc) : ((comp - 1.0) + sc);
    OUT[(size_t)row * C_ + col] = (float)((double)X[(size_t)row * C_ + col] * maskv);
  }
}

// =====================================================================
extern "C" void kernel_launch(void* const* d_in, const int* in_sizes, int n_in,
                              void* d_out, int out_size, void* d_ws, size_t ws_size,
                              hipStream_t stream) {
  const float* X = (const float*)d_in[0];
  const float* W = (const float*)d_in[1];
  const float* LNW = (const float*)d_in[2];
  const float* NOISE = (const float*)d_in[3];
  float* OUT = (float*)d_out;

  double* qkv = (double*)d_ws;                                  // 192 MB
  double* logits = (double*)((char*)d_ws + 8ull * BT * N3);     // +64 MB

  const double e = 1.0 / 1024.0;
  const double ls = (1.0 + sqrt(1.0 - 4.0 * e) - 2.0 * e) / (2.0 * e * e);
  const double denom = log(ls);

  qkv_mfma<<<dim3(N3 / 128, BT / 128), 256, 0, stream>>>(X, W, qkv);
  attn_mfma<<<dim3(8, 64), 512, 0, stream>>>(qkv, logits);
  finish_kernel<<<BT, 256, 0, stream>>>(logits, LNW, X, NOISE, OUT, ls, denom);
}

// Round 9
// 1732.815 us; speedup vs baseline: 3.0445x; 1.3916x over previous
//
#include <hip/hip_runtime.h>
#include <hip/hip_bf16.h>
#include <math.h>

#define BT 8192      // B*T rows
#define C_ 1024
#define N3 3072
#define T_ 2048

typedef double v4d __attribute__((ext_vector_type(4)));

// f64 MFMA 16x16x4 layouts (HW-verified via round-3 exact-integer probe):
//   A: m = l&15, k = l>>4        B: k = l>>4, n = l&15
//   D: col = l&15, row = (l>>4) + 4*reg      <-- NOT 4*(l>>4)+reg

// =====================================================================
// Kernel A: qkv = x @ w_qkv via f64 MFMA, 128x128 tile, BK=32.
// (measured ~94% of f64 MFMA peak — unchanged)
// =====================================================================
__device__ __forceinline__ void qkv_loadA(const float* __restrict__ X, int bm, int k0,
                                          int t, float4* fa) {
#pragma unroll
  for (int i = 0; i < 4; i++) {
    int idx = i * 256 + t;            // 0..1023 : 128 rows x 8 quads
    int row = idx >> 3, q4 = idx & 7;
    int c4 = q4 ^ (row & 7);          // pre-swizzled source column quad
    fa[i] = *(const float4*)(X + (size_t)(bm + row) * C_ + k0 + 4 * c4);
  }
}
__device__ __forceinline__ void qkv_loadB(const float* __restrict__ W, int bn, int k0,
                                          int t, float4* fb) {
#pragma unroll
  for (int i = 0; i < 4; i++) {
    int idx = i * 256 + t;            // 0..1023 : 32 rows x 32 quads
    int row = idx >> 5, q4 = idx & 31;
    fb[i] = *(const float4*)(W + (size_t)(k0 + row) * N3 + bn + 4 * q4);
  }
}
__device__ __forceinline__ void qkv_storeA(float* Al, int t, const float4* fa) {
  float4* A4 = (float4*)Al;
#pragma unroll
  for (int i = 0; i < 4; i++) {
    int idx = i * 256 + t;
    int row = idx >> 3, q4 = idx & 7;
    A4[row * 8 + q4] = fa[i];         // linear dest; source was pre-swizzled
  }
}
__device__ __forceinline__ void qkv_storeB(float* Bl, int t, const float4* fb) {
  float4* B4 = (float4*)Bl;
#pragma unroll
  for (int i = 0; i < 4; i++) {
    int idx = i * 256 + t;
    int row = idx >> 5, q4 = idx & 31;
    B4[row * 32 + q4] = fb[i];
  }
}

__global__ __launch_bounds__(256, 2) void qkv_mfma(const float* __restrict__ X,
                                                   const float* __restrict__ W,
                                                   double* __restrict__ QKV) {
  const int bn = blockIdx.x * 128, bm = blockIdx.y * 128;
  const int t = threadIdx.x;
  const int w = t >> 6, l = t & 63, g = l >> 4, ln = l & 15;
  const int m0 = (w >> 1) * 64, n0 = (w & 1) * 64;   // wave's 64x64 sub-tile

  __shared__ float Al[2][128 * 32];
  __shared__ float Bl[2][32 * 128];

  v4d acc[4][4];
#pragma unroll
  for (int i = 0; i < 4; i++)
#pragma unroll
    for (int j = 0; j < 4; j++) acc[i][j] = (v4d){0.0, 0.0, 0.0, 0.0};

  float4 fa[4], fb[4];
  qkv_loadA(X, bm, 0, t, fa);
  qkv_loadB(W, bn, 0, t, fb);
  qkv_storeA(Al[0], t, fa);
  qkv_storeB(Bl[0], t, fb);
  __syncthreads();

  for (int st = 0; st < 32; ++st) {
    const int cur = st & 1;
    if (st + 1 < 32) {                 // prefetch next stage into regs
      qkv_loadA(X, bm, (st + 1) * 32, t, fa);
      qkv_loadB(W, bn, (st + 1) * 32, t, fb);
    }
    const float* Ac = Al[cur];
    const float* Bc = Bl[cur];
#pragma unroll
    for (int s = 0; s < 8; s++) {      // 8 K-steps of 4
      double a[4], b[4];
#pragma unroll
      for (int mt = 0; mt < 4; mt++) {
        int row = m0 + mt * 16 + ln;
        a[mt] = (double)Ac[row * 32 + ((s ^ (row & 7)) << 2) + g];
      }
#pragma unroll
      for (int nt = 0; nt < 4; nt++)
        b[nt] = (double)Bc[(4 * s + g) * 128 + n0 + nt * 16 + ln];
#pragma unroll
      for (int mt = 0; mt < 4; mt++)
#pragma unroll
        for (int nt = 0; nt < 4; nt++)
          acc[mt][nt] = __builtin_amdgcn_mfma_f64_16x16x4f64(a[mt], b[nt], acc[mt][nt], 0, 0, 0);
    }
    if (st + 1 < 32) {
      qkv_storeA(Al[cur ^ 1], t, fa);
      qkv_storeB(Bl[cur ^ 1], t, fb);
    }
    __syncthreads();
  }

  // D row = g + 4r (verified layout)
#pragma unroll
  for (int mt = 0; mt < 4; mt++)
#pragma unroll
    for (int nt = 0; nt < 4; nt++)
#pragma unroll
      for (int r = 0; r < 4; r++) {
        size_t row = (size_t)(bm + m0 + mt * 16 + g + 4 * r);
        QKV[row * N3 + bn + n0 + nt * 16 + ln] = acc[mt][nt][r];
      }
}

// =====================================================================
// Kernel B: causal (QK^T/8) V via f64 MFMA — 8-wave 128-row super-tiles.
// Per-wave structure identical to the proven round-6 kernel (112 VGPR,
// no spill); the block is 512 threads so each staged K/V tile feeds
// 128 q-rows (2x reuse, half the barriers/HBM per unit work).
// launch_bounds(512, 2): 2nd arg acts as min BLOCKS/CU (CUDA semantics,
// observed round 8: (512,4) capped VGPR at 64 -> spills). 2 blocks/CU
// -> 16 waves/CU -> 128-VGPR budget >= the 112 this code needs.
// Super-tile j has nkt=4j+4 K-tiles; passes {15-px, px} -> constant 68.
// Grid 8x64 = 512 blocks = 2/CU (2x64 KB LDS). S^T = K*Q^T.
// =====================================================================
struct KVregs { double2 k[2]; double2 v[2]; };

__device__ __forceinline__ void kv_load(const double* __restrict__ QKV, size_t tokbase,
                                        int h, int kt, int t, KVregs& R) {
#pragma unroll
  for (int i = 0; i < 2; i++) {
    int idx = i * 512 + t;             // 0..1023 : 32 rows x 32 double2 slots
    int r = idx >> 5, q2 = idx & 31;
    int c2 = q2 ^ (r & 15);            // inverse-swizzled source pair
    size_t off = (tokbase + (size_t)(kt * 32 + r)) * N3 + h * 64 + 2 * c2;
    R.k[i] = *(const double2*)(QKV + off + C_);
    R.v[i] = *(const double2*)(QKV + off + 2 * C_);
  }
}
__device__ __forceinline__ void kv_store(double2* Kb, double2* Vb, int t, const KVregs& R) {
#pragma unroll
  for (int i = 0; i < 2; i++) {
    int idx = i * 512 + t;
    int r = idx >> 5, q2 = idx & 31;
    Kb[r * 32 + q2] = R.k[i];
    Vb[r * 32 + q2] = R.v[i];
  }
}

__global__ __launch_bounds__(512, 2) void attn_mfma(const double* __restrict__ QKV,
                                                    double* __restrict__ LOGITS) {
  const int px = blockIdx.x;                // 0..7
  const int bh = blockIdx.y;
  const int b = bh >> 4, h = bh & 15;
  const int t = threadIdx.x;
  const int w = t >> 6, l = t & 63, g = l >> 4, ln = l & 15;   // w in 0..7
  const size_t tokbase = (size_t)b * T_;

  __shared__ double2 Kl[2][1024];
  __shared__ double2 Vl[2][1024];

  for (int pass = 0; pass < 2; ++pass) {
    const int j = pass ? px : 15 - px;      // super-tile; nkt = 4j+4; sum = 68
    const int qrow = j * 128 + w * 16 + ln; // this lane's q (S^T col)
    const int qmaxw = j * 128 + w * 16 + 15;

    // Q fragments in registers for this pass: Q[qrow][4s+g]
    double qfrag[16];
#pragma unroll
    for (int s = 0; s < 16; s++)
      qfrag[s] = QKV[(tokbase + (size_t)qrow) * N3 + h * 64 + 4 * s + g];

    v4d acco[4];
#pragma unroll
    for (int nt = 0; nt < 4; nt++) acco[nt] = (v4d){0.0, 0.0, 0.0, 0.0};

    const int nkt = 4 * j + 4;
    KVregs R;
    kv_load(QKV, tokbase, h, 0, t, R);
    kv_store(Kl[0], Vl[0], t, R);
    __syncthreads();

    for (int kt = 0; kt < nkt; ++kt) {
      const int cur = kt & 1;
      if (kt + 1 < nkt) kv_load(QKV, tokbase, h, kt + 1, t, R);
      const double* Kd = (const double*)Kl[cur];
      const double* Vd = (const double*)Vl[cur];

      // ---- QK: S^T tiles, 2 independent accum chains per mt ----
      double sm[2][4];
#pragma unroll
      for (int mt = 0; mt < 2; mt++) {
        v4d s4a = (v4d){0.0, 0.0, 0.0, 0.0};
        v4d s4b = (v4d){0.0, 0.0, 0.0, 0.0};
        if (kt * 32 + mt * 16 <= qmaxw) {   // wave-uniform skip of masked tile
          const int r = mt * 16 + ln;       // K row (local)
#pragma unroll
          for (int s = 0; s < 8; s++) {
            int c = 4 * s + g;
            double a = Kd[r * 64 + (((c >> 1) ^ (r & 15)) << 1) + (c & 1)];
            s4a = __builtin_amdgcn_mfma_f64_16x16x4f64(a, qfrag[s], s4a, 0, 0, 0);
          }
#pragma unroll
          for (int s = 8; s < 16; s++) {
            int c = 4 * s + g;
            double a = Kd[r * 64 + (((c >> 1) ^ (r & 15)) << 1) + (c & 1)];
            s4b = __builtin_amdgcn_mfma_f64_16x16x4f64(a, qfrag[s], s4b, 0, 0, 0);
          }
        }
        v4d s4 = s4a + s4b;
#pragma unroll
        for (int r = 0; r < 4; r++) {
          int kg = kt * 32 + mt * 16 + g + 4 * r;   // verified D row = g + 4r
          sm[mt][r] = (kg <= qrow) ? s4[r] * 0.125 : 0.0;
        }
      }

      // ---- PV: O += S * V ; A-frag is lane-local register sm[s>>2][s&3] ----
#pragma unroll
      for (int s = 0; s < 8; s++) {
        if (kt * 32 + 4 * s <= qmaxw) {     // wave-uniform
          double a = sm[s >> 2][s & 3];     // = S[q=ln][4s+g]
          const int rv = 4 * s + g;         // V row (local)
#pragma unroll
          for (int nt = 0; nt < 4; nt++) {
            int cv = nt * 16 + ln;
            double bb = Vd[rv * 64 + (((cv >> 1) ^ (rv & 15)) << 1) + (cv & 1)];
            acco[nt] = __builtin_amdgcn_mfma_f64_16x16x4f64(a, bb, acco[nt], 0, 0, 0);
          }
        }
      }

      if (kt + 1 < nkt) kv_store(Kl[cur ^ 1], Vl[cur ^ 1], t, R);
      __syncthreads();
    }

    // O row = g + 4r (verified layout)
#pragma unroll
    for (int nt = 0; nt < 4; nt++)
#pragma unroll
      for (int r = 0; r < 4; r++) {
        size_t row = tokbase + (size_t)(j * 128 + w * 16 + g + 4 * r);
        LOGITS[row * C_ + h * 64 + nt * 16 + ln] = acco[nt][r];
      }
    // trailing __syncthreads of last kt ordered all LDS reads before next pass
  }
}

// =====================================================================
// Kernel C: LN + softmax + log-transform + mask  (f64 reductions)
// =====================================================================
__device__ __forceinline__ double blockReduceSumD(double val, double* sh) {
#pragma unroll
  for (int off = 32; off > 0; off >>= 1) val += __shfl_down(val, off, 64);
  int wid = threadIdx.x >> 6, lane = threadIdx.x & 63;
  if (lane == 0) sh[wid] = val;
  __syncthreads();
  double total = sh[0] + sh[1] + sh[2] + sh[3];
  __syncthreads();
  return total;
}
__device__ __forceinline__ double blockReduceMaxD(double val, double* sh) {
#pragma unroll
  for (int off = 32; off > 0; off >>= 1) val = fmax(val, __shfl_down(val, off, 64));
  int wid = threadIdx.x >> 6, lane = threadIdx.x & 63;
  if (lane == 0) sh[wid] = val;
  __syncthreads();
  double total = fmax(fmax(sh[0], sh[1]), fmax(sh[2], sh[3]));
  __syncthreads();
  return total;
}

__global__ __launch_bounds__(256) void finish_kernel(const double* __restrict__ LOGITS,
                                                     const float* __restrict__ LNW,
                                                     const float* __restrict__ X,
                                                     const float* __restrict__ NOISE,
                                                     float* __restrict__ OUT,
                                                     double log_scale, double denom) {
  __shared__ double sh[4];
  const int row = blockIdx.x;
  const int t = threadIdx.x;
  const double* lrow = LOGITS + (size_t)row * C_;
  double v[4];
#pragma unroll
  for (int j = 0; j < 4; j++) v[j] = lrow[t + j * 256];
  double psum = v[0] + v[1] + v[2] + v[3];
  double mu = blockReduceSumD(psum, sh) * (1.0 / 1024.0);
  double d2 = 0.0;
#pragma unroll
  for (int j = 0; j < 4; j++) { double d = v[j] - mu; d2 += d * d; }
  double var = blockReduceSumD(d2, sh) * (1.0 / 1024.0);
  double rstd = 1.0 / sqrt(var + 1e-5);
  double z[4];
#pragma unroll
  for (int j = 0; j < 4; j++)
    z[j] = (v[j] - mu) * rstd * (double)LNW[t + j * 256];
  double zmax = fmax(fmax(z[0], z[1]), fmax(z[2], z[3]));
  double m = blockReduceMaxD(zmax, sh);
  double e[4];
  double esum = 0.0;
#pragma unroll
  for (int j = 0; j < 4; j++) { e[j] = exp(z[j] - m); esum += e[j]; }
  double stot = blockReduceSumD(esum, sh);
#pragma unroll
  for (int j = 0; j < 4; j++) {
    int col = t + j * 256;
    double p = e[j] / stot;
    double sc = log(log_scale * p + 1.0) / denom;
    double comp = 1.0 - sc;
    double nz = (double)NOISE[(size_t)row * C_ + col];
    double maskv = (nz >= comp) ? (comp + sc) : ((comp - 1.0) + sc);
    OUT[(size_t)row * C_ + col] = (float)((double)X[(size_t)row * C_ + col] * maskv);
  }
}

// =====================================================================
extern "C" void kernel_launch(void* const* d_in, const int* in_sizes, int n_in,
                              void* d_out, int out_size, void* d_ws, size_t ws_size,
                              hipStream_t stream) {
  const float* X = (const float*)d_in[0];
  const float* W = (const float*)d_in[1];
  const float* LNW = (const float*)d_in[2];
  const float* NOISE = (const float*)d_in[3];
  float* OUT = (float*)d_out;

  double* qkv = (double*)d_ws;                                  // 192 MB
  double* logits = (double*)((char*)d_ws + 8ull * BT * N3);     // +64 MB

  const double e = 1.0 / 1024.0;
  const double ls = (1.0 + sqrt(1.0 - 4.0 * e) - 2.0 * e) / (2.0 * e * e);
  const double denom = log(ls);

  qkv_mfma<<<dim3(N3 / 128, BT / 128), 256, 0, stream>>>(X, W, qkv);
  attn_mfma<<<dim3(8, 64), 512, 0, stream>>>(qkv, logits);
  finish_kernel<<<BT, 256, 0, stream>>>(logits, LNW, X, NOISE, OUT, ls, denom);
}